// Round 8
// baseline (127.466 us; speedup 1.0000x reference)
//
#include <hip/hip_runtime.h>

// Problem constants: B=2, L=16, N=10000, FIN=8, H=64, P=12, E=80000, K=3
#define NN   10000
#define LL   16
#define FINC 8
#define HH   64
#define PP   12
#define EE   80000
#define BLH  256   // (b,lp,h) = 2*2*64 — only l=14,15 feed out[:,:,-1] (K=3, pad=1)
#define CAP  64    // per-row edge bucket capacity; E/N = 8, P(deg>64) ~ 0

// ---------------------------------------------------------------------------
// k1 v2: 256 fat blocks, grid-stride nodes. W_in in registers (reused ~39x),
// x via wave-uniform broadcast loads, coalesced 1KB stores. Zeroes deg.
// ---------------------------------------------------------------------------
__global__ __launch_bounds__(256) void k1_input_proj(
        const float* __restrict__ x, const float* __restrict__ W_in,
        const float* __restrict__ b_in, float* __restrict__ hsmall,
        int* __restrict__ deg) {
    const int t  = threadIdx.x;
    const int bl = t >> 6;          // wave-uniform (b*2+lp)
    const int h  = t & 63;
    const int b  = bl >> 1, lp = bl & 1;
    float w[FINC];
#pragma unroll
    for (int f = 0; f < FINC; ++f) w[f] = W_in[f * HH + h];
    const float bias = b_in[h];
    const float* xb = x + (size_t)(b * LL + 14 + lp) * NN * FINC;
    for (int n = blockIdx.x; n < NN; n += 256) {
        float4 xa = *(const float4*)&xb[n * 8];      // wave-uniform -> broadcast
        float4 xc = *(const float4*)&xb[n * 8 + 4];
        float acc = bias;
        acc = fmaf(xa.x, w[0], acc); acc = fmaf(xa.y, w[1], acc);
        acc = fmaf(xa.z, w[2], acc); acc = fmaf(xa.w, w[3], acc);
        acc = fmaf(xc.x, w[4], acc); acc = fmaf(xc.y, w[5], acc);
        acc = fmaf(xc.z, w[6], acc); acc = fmaf(xc.w, w[7], acc);
        hsmall[(size_t)n * BLH + t] = fmaxf(acc, 0.f);
        if (t == 0) deg[n] = 0;
    }
}

// ---------------------------------------------------------------------------
// k2: bucketed CSR build + pack W_tcn taps {0,1} into Wt[k][o] (k = lp*64+i).
// ---------------------------------------------------------------------------
__global__ __launch_bounds__(256) void k2_build(
        const int* __restrict__ row, const int* __restrict__ col,
        const float* __restrict__ vals, int* __restrict__ deg,
        int2* __restrict__ bucket, const float* __restrict__ W_tcn,
        float* __restrict__ Wt) {
    int e = blockIdx.x * 256 + threadIdx.x;
    if (e < EE) {
        int r = row[e];
        int pos = atomicAdd(&deg[r], 1);
        if (pos < CAP)
            bucket[(size_t)r * CAP + pos] = make_int2(col[e], __float_as_int(vals[e]));
    } else if (e < EE + 3 * HH * HH) {
        int f = e - EE;                 // linear index into W_tcn [o][i][k3]
        int kk = f % 3;
        if (kk < 2) {
            int o = f / (HH * 3);
            int i = (f / 3) % HH;
            Wt[(kk * HH + i) * HH + o] = W_tcn[f];
        }
    }
}

// ---------------------------------------------------------------------------
// k3: gather-aggregate, zero LDS. One wave per node; metadata via one
// coalesced 512B load + shfl broadcast (entries >= deg masked to {0, 0.0});
// 8 independent row loads in flight.
// ---------------------------------------------------------------------------
__global__ __launch_bounds__(256) void k3_gather(
        const float* __restrict__ hsmall, const int* __restrict__ deg,
        const int2* __restrict__ bucket, float* __restrict__ h2) {
    const int wave = threadIdx.x >> 6;
    const int lane = threadIdx.x & 63;
    const int n = blockIdx.x * 4 + wave;
    const int dn  = min(deg[n], CAP);
    const int dnp = (dn + 7) & ~7;
    const int2 meta = bucket[(size_t)n * CAP + lane];   // poison beyond dn — masked

    float4 acc = make_float4(0.f, 0.f, 0.f, 0.f);
    for (int i = 0; i < dnp; i += 8) {
        int   c[8];
        float v[8];
#pragma unroll
        for (int j = 0; j < 8; ++j) {
            int idx = i + j;
            int   cc = __shfl(meta.x, idx);
            float vv = __int_as_float(__shfl(meta.y, idx));
            bool ok = idx < dn;
            c[j] = ok ? cc : 0;
            v[j] = ok ? vv : 0.f;
        }
        float4 hv[8];
#pragma unroll
        for (int j = 0; j < 8; ++j)
            hv[j] = *(const float4*)&hsmall[(size_t)c[j] * BLH + lane * 4];
#pragma unroll
        for (int j = 0; j < 8; ++j) {
            acc.x = fmaf(v[j], hv[j].x, acc.x);
            acc.y = fmaf(v[j], hv[j].y, acc.y);
            acc.z = fmaf(v[j], hv[j].z, acc.z);
            acc.w = fmaf(v[j], hv[j].w, acc.w);
        }
    }
    float4 r = make_float4(fmaxf(acc.x, 0.f), fmaxf(acc.y, 0.f),
                           fmaxf(acc.z, 0.f), fmaxf(acc.w, 0.f));
    *(float4*)&h2[(size_t)n * BLH + lane * 4] = r;
}

// ---------------------------------------------------------------------------
// k4 v-F: head GEMM, occupancy-first.  M=20000 rows (n,b), K=128, N=64 (o).
// 1024 threads = 64 rows x 16 wave-uniform o-groups; thread = 1 row x 4 o
// over all 128 k (acc[4], no split-K, no reduction).  5008 waves total
// (~4.9/SIMD vs 2.4 before).  LDS = s_tile [row][129] only (33 KB,
// conflict-free staging writes AND K-loop reads); W/bias/W_out/b_out all on
// the wave-uniform scalar-load path; s_tile region reused as hl[o*65+row].
// ---------------------------------------------------------------------------
__global__ __launch_bounds__(1024) void k4_head(
        const float* __restrict__ h2, const float* __restrict__ Wt,
        const float* __restrict__ b_tcn, const float* __restrict__ W_out,
        const float* __restrict__ b_out, float* __restrict__ y) {
    __shared__ float pool[64 * 129];   // 33.0 KB: s_tile[row][k], then hl[o*65+row]
    const int t   = threadIdx.x;       // 0..1023
    const int row = t & 63;            // row = nn*2 + b
    const int og  = __builtin_amdgcn_readfirstlane(t >> 6);   // 0..15, wave-uniform
    const int n0  = blockIdx.x * 32;

    // stage s_tile: thread reads one float4 of h2 (coalesced), writes 4 b32
    // at pool[row*129 + k0..k0+3] (4-way worst-case banking ~= free)
    const float4* h2v = (const float4*)h2;
    for (int idx4 = t; idx4 < 32 * (BLH / 4); idx4 += 1024) {
        int nn = idx4 >> 6, j4 = idx4 & 63;
        int r  = nn * 2 + (j4 >> 5);
        int k0 = (j4 & 31) * 4;
        float4 v = make_float4(0.f, 0.f, 0.f, 0.f);
        if (n0 + nn < NN) v = h2v[(size_t)(n0 + nn) * (BLH / 4) + j4];
        pool[r * 129 + k0 + 0] = v.x;
        pool[r * 129 + k0 + 1] = v.y;
        pool[r * 129 + k0 + 2] = v.z;
        pool[r * 129 + k0 + 3] = v.w;
    }
    __syncthreads();

    const float4* Wt4 = (const float4*)Wt;    // Wt[k*64+o] -> float4 idx k*16 + og
    float a0 = 0.f, a1 = 0.f, a2 = 0.f, a3 = 0.f;
#pragma unroll 4
    for (int k = 0; k < 128; ++k) {
        float  sv = pool[row * 129 + k];      // bank (row+k)%32 — conflict-free
        float4 w  = Wt4[k * 16 + og];         // wave-uniform -> s_load_dwordx4
        a0 = fmaf(sv, w.x, a0);
        a1 = fmaf(sv, w.y, a1);
        a2 = fmaf(sv, w.z, a2);
        a3 = fmaf(sv, w.w, a3);
    }
    __syncthreads();   // all s_tile reads done; pool reusable as hl

    float4 bt = ((const float4*)b_tcn)[og];   // wave-uniform scalar load
    pool[(og * 4 + 0) * 65 + row] = fmaxf(a0 + bt.x, 0.f);
    pool[(og * 4 + 1) * 65 + row] = fmaxf(a1 + bt.y, 0.f);
    pool[(og * 4 + 2) * 65 + row] = fmaxf(a2 + bt.z, 0.f);
    pool[(og * 4 + 3) * 65 + row] = fmaxf(a3 + bt.w, 0.f);
    __syncthreads();

    // epilogue: 768 outputs = 64 rows x 12 p; p wave-uniform; W_out via
    // wave-uniform scalar loads (no LDS copy)
    if (t < 64 * PP) {
        int r2 = t & 63, p = t >> 6;          // p in 0..11
        int n = n0 + (r2 >> 1), b = r2 & 1;
        float yy = b_out[p];
#pragma unroll 8
        for (int o = 0; o < HH; ++o)
            yy = fmaf(pool[o * 65 + r2], W_out[o * PP + p], yy);
        if (n < NN) y[((size_t)(b * PP + p)) * NN + n] = yy;
    }
}

// ---------------------------------------------------------------------------
extern "C" void kernel_launch(void* const* d_in, const int* in_sizes, int n_in,
                              void* d_out, int out_size, void* d_ws, size_t ws_size,
                              hipStream_t stream) {
    const float* x     = (const float*)d_in[0];
    const int*   row   = (const int*)d_in[1];
    const int*   col   = (const int*)d_in[2];
    const float* vals  = (const float*)d_in[3];
    const float* W_in  = (const float*)d_in[4];
    const float* b_in  = (const float*)d_in[5];
    const float* W_tcn = (const float*)d_in[6];
    const float* b_tcn = (const float*)d_in[7];
    const float* W_out = (const float*)d_in[8];
    const float* b_out = (const float*)d_in[9];
    float* y = (float*)d_out;

    char* ws = (char*)d_ws;
    float* hsmall = (float*)(ws);                    // 10,240,000 B
    int*   deg    = (int*)(ws + 10240000);           //     40,000 B
    int2*  bucket = (int2*)(ws + 10280000);          //  5,120,000 B
    float* h2     = (float*)(ws + 15400000);         // 10,240,000 B
    float* Wt     = (float*)(ws + 25640000);         //     32,768 B

    k1_input_proj<<<256, 256, 0, stream>>>(x, W_in, b_in, hsmall, deg);
    k2_build<<<(EE + 3 * HH * HH + 255) / 256, 256, 0, stream>>>(
        row, col, vals, deg, bucket, W_tcn, Wt);
    k3_gather<<<NN / 4, 256, 0, stream>>>(hsmall, deg, bucket, h2);
    // 32 nodes (64 rows) per block, 1024 threads (16 o-groups) -> 313 blocks
    k4_head<<<(NN + 31) / 32, 1024, 0, stream>>>(h2, Wt, b_tcn, W_out, b_out, y);
}

// Round 9
// 117.394 us; speedup vs baseline: 1.0858x; 1.0858x over previous
//
#include <hip/hip_runtime.h>

// Problem constants: B=2, L=16, N=10000, FIN=8, H=64, P=12, E=80000, K=3
#define NN   10000
#define LL   16
#define FINC 8
#define HH   64
#define PP   12
#define EE   80000
#define BLH  256   // (b,lp,h) = 2*2*64 — only l=14,15 feed out[:,:,-1] (K=3, pad=1)
#define CAP  64    // per-row edge bucket capacity; E/N = 8, P(deg>64) ~ 0

// ---------------------------------------------------------------------------
// k1 v3: 2500 blocks x 256 threads, 4 nodes per block (fully unrolled).
// W_in held in 8 registers; x read via wave-uniform scalar loads; no LDS,
// no sync; 4 independent iterations give MLP. Blocks 0..39 zero deg.
// hsmall[n*256 + (b*2+lp)*64 + h] = relu(b_in[h] + sum_f x[b,14+lp,n,f]*W_in[f,h])
// ---------------------------------------------------------------------------
__global__ __launch_bounds__(256) void k1_input_proj(
        const float* __restrict__ x, const float* __restrict__ W_in,
        const float* __restrict__ b_in, float* __restrict__ hsmall,
        int* __restrict__ deg) {
    const int t  = threadIdx.x;
    const int bl = __builtin_amdgcn_readfirstlane(t >> 6);  // wave-uniform (b*2+lp)
    const int h  = t & 63;
    const int b  = bl >> 1, lp = bl & 1;

    if (blockIdx.x < 40) {                 // zero deg (10000 ints over 40 blocks)
        int di = blockIdx.x * 256 + t;
        if (di < NN) deg[di] = 0;
    }

    float w[FINC];
#pragma unroll
    for (int f = 0; f < FINC; ++f) w[f] = W_in[f * HH + h];   // coalesced, L2-hot
    const float bias = b_in[h];
    const float* xb = x + (size_t)(b * LL + 14 + lp) * NN * FINC;
    const int g = blockIdx.x * 4;

#pragma unroll
    for (int nn = 0; nn < 4; ++nn) {
        const int n = g + nn;
        float4 xa = *(const float4*)&xb[(size_t)n * 8];       // uniform -> s_load
        float4 xc = *(const float4*)&xb[(size_t)n * 8 + 4];
        float acc = bias;
        acc = fmaf(xa.x, w[0], acc); acc = fmaf(xa.y, w[1], acc);
        acc = fmaf(xa.z, w[2], acc); acc = fmaf(xa.w, w[3], acc);
        acc = fmaf(xc.x, w[4], acc); acc = fmaf(xc.y, w[5], acc);
        acc = fmaf(xc.z, w[6], acc); acc = fmaf(xc.w, w[7], acc);
        hsmall[(size_t)n * BLH + t] = fmaxf(acc, 0.f);        // coalesced 1KB/wave-grp
    }
}

// ---------------------------------------------------------------------------
// k2: bucketed CSR build + pack W_tcn taps {0,1} into Wt[k][o] (k = lp*64+i).
// ---------------------------------------------------------------------------
__global__ __launch_bounds__(256) void k2_build(
        const int* __restrict__ row, const int* __restrict__ col,
        const float* __restrict__ vals, int* __restrict__ deg,
        int2* __restrict__ bucket, const float* __restrict__ W_tcn,
        float* __restrict__ Wt) {
    int e = blockIdx.x * 256 + threadIdx.x;
    if (e < EE) {
        int r = row[e];
        int pos = atomicAdd(&deg[r], 1);
        if (pos < CAP)
            bucket[(size_t)r * CAP + pos] = make_int2(col[e], __float_as_int(vals[e]));
    } else if (e < EE + 3 * HH * HH) {
        int f = e - EE;                 // linear index into W_tcn [o][i][k3]
        int kk = f % 3;
        if (kk < 2) {
            int o = f / (HH * 3);
            int i = (f / 3) % HH;
            Wt[(kk * HH + i) * HH + o] = W_tcn[f];
        }
    }
}

// ---------------------------------------------------------------------------
// k3: gather-aggregate, zero LDS. One wave per node; metadata via one
// coalesced 512B load + shfl broadcast (entries >= deg masked to {0, 0.0});
// 8 independent row loads in flight.
// ---------------------------------------------------------------------------
__global__ __launch_bounds__(256) void k3_gather(
        const float* __restrict__ hsmall, const int* __restrict__ deg,
        const int2* __restrict__ bucket, float* __restrict__ h2) {
    const int wave = threadIdx.x >> 6;
    const int lane = threadIdx.x & 63;
    const int n = blockIdx.x * 4 + wave;
    const int dn  = min(deg[n], CAP);
    const int dnp = (dn + 7) & ~7;
    const int2 meta = bucket[(size_t)n * CAP + lane];   // poison beyond dn — masked

    float4 acc = make_float4(0.f, 0.f, 0.f, 0.f);
    for (int i = 0; i < dnp; i += 8) {
        int   c[8];
        float v[8];
#pragma unroll
        for (int j = 0; j < 8; ++j) {
            int idx = i + j;
            int   cc = __shfl(meta.x, idx);
            float vv = __int_as_float(__shfl(meta.y, idx));
            bool ok = idx < dn;
            c[j] = ok ? cc : 0;
            v[j] = ok ? vv : 0.f;
        }
        float4 hv[8];
#pragma unroll
        for (int j = 0; j < 8; ++j)
            hv[j] = *(const float4*)&hsmall[(size_t)c[j] * BLH + lane * 4];
#pragma unroll
        for (int j = 0; j < 8; ++j) {
            acc.x = fmaf(v[j], hv[j].x, acc.x);
            acc.y = fmaf(v[j], hv[j].y, acc.y);
            acc.z = fmaf(v[j], hv[j].z, acc.z);
            acc.w = fmaf(v[j], hv[j].w, acc.w);
        }
    }
    float4 r = make_float4(fmaxf(acc.x, 0.f), fmaxf(acc.y, 0.f),
                           fmaxf(acc.z, 0.f), fmaxf(acc.w, 0.f));
    *(float4*)&h2[(size_t)n * BLH + lane * 4] = r;
}

// ---------------------------------------------------------------------------
// k4: head GEMM, split-K x2 in-block (r7 known-good).  M=20000 rows (n,b),
// K=128, N=64 (o).  512 threads = 64 rows x 4 col-groups x 2 K-halves;
// thread = 1 row x 16 o over 64 k (acc[16]: 16 FMA per LDS read).  W via
// wave-uniform scalar loads; s_tile [k][row] stride-65; cross-half reduction
// through stride-17 LDS; pool reused as hl[o][row].
// ---------------------------------------------------------------------------
__global__ __launch_bounds__(512) void k4_head(
        const float* __restrict__ h2, const float* __restrict__ Wt,
        const float* __restrict__ b_tcn, const float* __restrict__ W_out,
        const float* __restrict__ b_out, float* __restrict__ y) {
    __shared__ float pool[128 * 65];   // 33.3 KB: s_tile, then hl[o*65+row]
    __shared__ float red[256 * 17];    // 17.4 KB: kq=1 partials, padded
    __shared__ float Wo[HH * PP];      // 3 KB
    const int t   = threadIdx.x;       // 0..511
    const int row = t & 63;
    const int cg  = __builtin_amdgcn_readfirstlane((t >> 6) & 3);  // wave-uniform
    const int kq  = __builtin_amdgcn_readfirstlane(t >> 8);        // wave-uniform
    const int n0  = blockIdx.x * 32;

    for (int idx = t; idx < HH * PP; idx += 512) Wo[idx] = W_out[idx];
    // stage s_tile[k][row] (conflict-free: bank = (65k+row)%32)
    for (int idx = t; idx < 32 * BLH; idx += 512) {
        int nn = idx >> 8, j = idx & 255;
        float v = (n0 + nn < NN) ? h2[(size_t)(n0 + nn) * BLH + j] : 0.f;
        pool[(j & 127) * 65 + nn * 2 + (j >> 7)] = v;
    }
    __syncthreads();

    const float4* Wt4 = (const float4*)Wt;    // Wt[k*64+o] -> float4 idx k*16+o/4
    float acc[16];
#pragma unroll
    for (int j = 0; j < 16; ++j) acc[j] = 0.f;

    const int kbase = kq * 64;
#pragma unroll 4
    for (int kk = 0; kk < 64; ++kk) {
        const int k = kbase + kk;
        float sv = pool[k * 65 + row];
        float4 w0 = Wt4[k * 16 + cg * 4 + 0];   // wave-uniform -> s_load_dwordx4
        float4 w1 = Wt4[k * 16 + cg * 4 + 1];
        float4 w2 = Wt4[k * 16 + cg * 4 + 2];
        float4 w3 = Wt4[k * 16 + cg * 4 + 3];
        acc[ 0] = fmaf(sv, w0.x, acc[ 0]); acc[ 1] = fmaf(sv, w0.y, acc[ 1]);
        acc[ 2] = fmaf(sv, w0.z, acc[ 2]); acc[ 3] = fmaf(sv, w0.w, acc[ 3]);
        acc[ 4] = fmaf(sv, w1.x, acc[ 4]); acc[ 5] = fmaf(sv, w1.y, acc[ 5]);
        acc[ 6] = fmaf(sv, w1.z, acc[ 6]); acc[ 7] = fmaf(sv, w1.w, acc[ 7]);
        acc[ 8] = fmaf(sv, w2.x, acc[ 8]); acc[ 9] = fmaf(sv, w2.y, acc[ 9]);
        acc[10] = fmaf(sv, w2.z, acc[10]); acc[11] = fmaf(sv, w2.w, acc[11]);
        acc[12] = fmaf(sv, w3.x, acc[12]); acc[13] = fmaf(sv, w3.y, acc[13]);
        acc[14] = fmaf(sv, w3.z, acc[14]); acc[15] = fmaf(sv, w3.w, acc[15]);
    }
    // kq=1 partials -> LDS (stride 17: odd stride, 2 lanes/bank = free)
    if (kq == 1) {
#pragma unroll
        for (int j = 0; j < 16; ++j) red[(t - 256) * 17 + j] = acc[j];
    }
    __syncthreads();   // also: all s_tile reads done; pool reusable

    if (kq == 0) {
        const float4* bt4 = (const float4*)b_tcn;   // wave-uniform scalar loads
        float4 b0 = bt4[cg * 4 + 0], b1 = bt4[cg * 4 + 1];
        float4 b2 = bt4[cg * 4 + 2], b3 = bt4[cg * 4 + 3];
        float bt[16] = {b0.x, b0.y, b0.z, b0.w, b1.x, b1.y, b1.z, b1.w,
                        b2.x, b2.y, b2.z, b2.w, b3.x, b3.y, b3.z, b3.w};
#pragma unroll
        for (int j = 0; j < 16; ++j) {
            float s2 = acc[j] + red[t * 17 + j];
            pool[(cg * 16 + j) * 65 + row] = fmaxf(s2 + bt[j], 0.f);  // hl[o][row]
        }
    }
    __syncthreads();

    // epilogue: 768 outputs = 64 rows (n,b encoded) x 12 p
    for (int out = t; out < 64 * PP; out += 512) {
        int r2 = out & 63, p = out >> 6;       // p in 0..11
        int n = n0 + (r2 >> 1), b = r2 & 1;
        float yy = b_out[p];
#pragma unroll 8
        for (int o = 0; o < HH; ++o)
            yy = fmaf(pool[o * 65 + r2], Wo[o * PP + p], yy);
        if (n < NN) y[((size_t)(b * PP + p)) * NN + n] = yy;
    }
}

// ---------------------------------------------------------------------------
extern "C" void kernel_launch(void* const* d_in, const int* in_sizes, int n_in,
                              void* d_out, int out_size, void* d_ws, size_t ws_size,
                              hipStream_t stream) {
    const float* x     = (const float*)d_in[0];
    const int*   row   = (const int*)d_in[1];
    const int*   col   = (const int*)d_in[2];
    const float* vals  = (const float*)d_in[3];
    const float* W_in  = (const float*)d_in[4];
    const float* b_in  = (const float*)d_in[5];
    const float* W_tcn = (const float*)d_in[6];
    const float* b_tcn = (const float*)d_in[7];
    const float* W_out = (const float*)d_in[8];
    const float* b_out = (const float*)d_in[9];
    float* y = (float*)d_out;

    char* ws = (char*)d_ws;
    float* hsmall = (float*)(ws);                    // 10,240,000 B
    int*   deg    = (int*)(ws + 10240000);           //     40,000 B
    int2*  bucket = (int2*)(ws + 10280000);          //  5,120,000 B
    float* h2     = (float*)(ws + 15400000);         // 10,240,000 B
    float* Wt     = (float*)(ws + 25640000);         //     32,768 B

    k1_input_proj<<<NN / 4, 256, 0, stream>>>(x, W_in, b_in, hsmall, deg);
    k2_build<<<(EE + 3 * HH * HH + 255) / 256, 256, 0, stream>>>(
        row, col, vals, deg, bucket, W_tcn, Wt);
    k3_gather<<<NN / 4, 256, 0, stream>>>(hsmall, deg, bucket, h2);
    // 32 nodes (64 rows) per block, 512 threads (split-K x2) -> 313 blocks
    k4_head<<<(NN + 31) / 32, 512, 0, stream>>>(h2, Wt, b_tcn, W_out, b_out, y);
}

// Round 10
// 111.635 us; speedup vs baseline: 1.1418x; 1.0516x over previous
//
#include <hip/hip_runtime.h>

// Problem constants: B=2, L=16, N=10000, FIN=8, H=64, P=12, E=80000, K=3
#define NN   10000
#define LL   16
#define FINC 8
#define HH   64
#define PP   12
#define EE   80000
#define BLH  256   // (b,lp,h) = 2*2*64 — only l=14,15 feed out[:,:,-1] (K=3, pad=1)
#define CAP  64    // per-row edge bucket capacity; E/N = 8, P(deg>64) ~ 0
#define RS   132   // k4 row stride (pad 128+4): 16B-aligned, odd bank phase per row

// ---------------------------------------------------------------------------
// k1 v3: 2500 blocks x 256 threads, 4 nodes per block (fully unrolled).
// W_in held in 8 registers; x read via wave-uniform scalar loads; no LDS,
// no sync. Blocks 0..39 zero deg.
// ---------------------------------------------------------------------------
__global__ __launch_bounds__(256) void k1_input_proj(
        const float* __restrict__ x, const float* __restrict__ W_in,
        const float* __restrict__ b_in, float* __restrict__ hsmall,
        int* __restrict__ deg) {
    const int t  = threadIdx.x;
    const int bl = __builtin_amdgcn_readfirstlane(t >> 6);  // wave-uniform (b*2+lp)
    const int h  = t & 63;
    const int b  = bl >> 1, lp = bl & 1;

    if (blockIdx.x < 40) {                 // zero deg (10000 ints over 40 blocks)
        int di = blockIdx.x * 256 + t;
        if (di < NN) deg[di] = 0;
    }

    float w[FINC];
#pragma unroll
    for (int f = 0; f < FINC; ++f) w[f] = W_in[f * HH + h];   // coalesced, L2-hot
    const float bias = b_in[h];
    const float* xb = x + (size_t)(b * LL + 14 + lp) * NN * FINC;
    const int g = blockIdx.x * 4;

#pragma unroll
    for (int nn = 0; nn < 4; ++nn) {
        const int n = g + nn;
        float4 xa = *(const float4*)&xb[(size_t)n * 8];       // uniform -> s_load
        float4 xc = *(const float4*)&xb[(size_t)n * 8 + 4];
        float acc = bias;
        acc = fmaf(xa.x, w[0], acc); acc = fmaf(xa.y, w[1], acc);
        acc = fmaf(xa.z, w[2], acc); acc = fmaf(xa.w, w[3], acc);
        acc = fmaf(xc.x, w[4], acc); acc = fmaf(xc.y, w[5], acc);
        acc = fmaf(xc.z, w[6], acc); acc = fmaf(xc.w, w[7], acc);
        hsmall[(size_t)n * BLH + t] = fmaxf(acc, 0.f);
    }
}

// ---------------------------------------------------------------------------
// k2: bucketed CSR build + pack W_tcn taps {0,1} into Wt[k][o] (k = lp*64+i).
// ---------------------------------------------------------------------------
__global__ __launch_bounds__(256) void k2_build(
        const int* __restrict__ row, const int* __restrict__ col,
        const float* __restrict__ vals, int* __restrict__ deg,
        int2* __restrict__ bucket, const float* __restrict__ W_tcn,
        float* __restrict__ Wt) {
    int e = blockIdx.x * 256 + threadIdx.x;
    if (e < EE) {
        int r = row[e];
        int pos = atomicAdd(&deg[r], 1);
        if (pos < CAP)
            bucket[(size_t)r * CAP + pos] = make_int2(col[e], __float_as_int(vals[e]));
    } else if (e < EE + 3 * HH * HH) {
        int f = e - EE;                 // linear index into W_tcn [o][i][k3]
        int kk = f % 3;
        if (kk < 2) {
            int o = f / (HH * 3);
            int i = (f / 3) % HH;
            Wt[(kk * HH + i) * HH + o] = W_tcn[f];
        }
    }
}

// ---------------------------------------------------------------------------
// k3: gather-aggregate, zero LDS. One wave per node; metadata via one
// coalesced 512B load + shfl broadcast (entries >= deg masked to {0, 0.0});
// 8 independent row loads in flight.
// ---------------------------------------------------------------------------
__global__ __launch_bounds__(256) void k3_gather(
        const float* __restrict__ hsmall, const int* __restrict__ deg,
        const int2* __restrict__ bucket, float* __restrict__ h2) {
    const int wave = threadIdx.x >> 6;
    const int lane = threadIdx.x & 63;
    const int n = blockIdx.x * 4 + wave;
    const int dn  = min(deg[n], CAP);
    const int dnp = (dn + 7) & ~7;
    const int2 meta = bucket[(size_t)n * CAP + lane];   // poison beyond dn — masked

    float4 acc = make_float4(0.f, 0.f, 0.f, 0.f);
    for (int i = 0; i < dnp; i += 8) {
        int   c[8];
        float v[8];
#pragma unroll
        for (int j = 0; j < 8; ++j) {
            int idx = i + j;
            int   cc = __shfl(meta.x, idx);
            float vv = __int_as_float(__shfl(meta.y, idx));
            bool ok = idx < dn;
            c[j] = ok ? cc : 0;
            v[j] = ok ? vv : 0.f;
        }
        float4 hv[8];
#pragma unroll
        for (int j = 0; j < 8; ++j)
            hv[j] = *(const float4*)&hsmall[(size_t)c[j] * BLH + lane * 4];
#pragma unroll
        for (int j = 0; j < 8; ++j) {
            acc.x = fmaf(v[j], hv[j].x, acc.x);
            acc.y = fmaf(v[j], hv[j].y, acc.y);
            acc.z = fmaf(v[j], hv[j].z, acc.z);
            acc.w = fmaf(v[j], hv[j].w, acc.w);
        }
    }
    float4 r = make_float4(fmaxf(acc.x, 0.f), fmaxf(acc.y, 0.f),
                           fmaxf(acc.z, 0.f), fmaxf(acc.w, 0.f));
    *(float4*)&h2[(size_t)n * BLH + lane * 4] = r;
}

// ---------------------------------------------------------------------------
// k4: head GEMM, split-K x2, ROW-MAJOR s_tile + ds_read_b128.
// M=20000 rows (n,b), K=128, N=64 (o). 512 threads = 64 rows x 4 col-groups
// x 2 K-halves; thread = 1 row x 16 o over 64 k, 4 k per LDS op:
// 16 ds_read_b128 (vs 64 ds_read_b32) per thread; Wt via wave-uniform
// s_loads (4x contiguous 64B per 4-k group); stride-17 LDS reduction;
// pool reused as hl[o][row].  s_tile[row][k] = h2[n*256 + b*128 + k]
// (contiguous in k — that's what makes b128 possible).
// ---------------------------------------------------------------------------
__global__ __launch_bounds__(512) void k4_head(
        const float* __restrict__ h2, const float* __restrict__ Wt,
        const float* __restrict__ b_tcn, const float* __restrict__ W_out,
        const float* __restrict__ b_out, float* __restrict__ y) {
    __shared__ float pool[64 * RS];    // 33.8 KB: s_tile[row][k], then hl[o*65+row]
    __shared__ float red[256 * 17];    // 17.4 KB: kq=1 partials, padded
    __shared__ float Wo[HH * PP];      // 3 KB
    const int t   = threadIdx.x;       // 0..511
    const int row = t & 63;
    const int cg  = __builtin_amdgcn_readfirstlane((t >> 6) & 3);  // wave-uniform
    const int kq  = __builtin_amdgcn_readfirstlane(t >> 8);        // wave-uniform
    const int n0  = blockIdx.x * 32;

    for (int idx = t; idx < HH * PP; idx += 512) Wo[idx] = W_out[idx];
    // stage s_tile[row][k]: coalesced float4 loads, aligned b128 LDS writes
    const float4* h2v = (const float4*)h2;
    for (int idx4 = t; idx4 < 32 * (BLH / 4); idx4 += 512) {
        int nn = idx4 >> 6, q = idx4 & 63;       // q: b=q>>5, k0=(q&31)*4
        int r  = nn * 2 + (q >> 5);
        int k0 = (q & 31) * 4;
        float4 v = make_float4(0.f, 0.f, 0.f, 0.f);
        if (n0 + nn < NN) v = h2v[(size_t)(n0 + nn) * (BLH / 4) + q];
        *(float4*)&pool[r * RS + k0] = v;        // RS*4 % 16 == 0 -> aligned
    }
    __syncthreads();

    const float4* Wt4 = (const float4*)Wt;    // Wt[k*64+o] -> float4 idx k*16+o/4
    float acc[16];
#pragma unroll
    for (int j = 0; j < 16; ++j) acc[j] = 0.f;

    const int kbase = kq * 64;
#pragma unroll 4
    for (int kk = 0; kk < 16; ++kk) {
        const int k0 = kbase + kk * 4;
        float4 s4 = *(const float4*)&pool[row * RS + k0];   // 1 ds_read_b128 = 4 k
        float sv[4] = {s4.x, s4.y, s4.z, s4.w};
#pragma unroll
        for (int j = 0; j < 4; ++j) {
            const int k = k0 + j;
            float4 w0 = Wt4[k * 16 + cg * 4 + 0];   // 4x16B contiguous -> s_load
            float4 w1 = Wt4[k * 16 + cg * 4 + 1];
            float4 w2 = Wt4[k * 16 + cg * 4 + 2];
            float4 w3 = Wt4[k * 16 + cg * 4 + 3];
            float v = sv[j];
            acc[ 0] = fmaf(v, w0.x, acc[ 0]); acc[ 1] = fmaf(v, w0.y, acc[ 1]);
            acc[ 2] = fmaf(v, w0.z, acc[ 2]); acc[ 3] = fmaf(v, w0.w, acc[ 3]);
            acc[ 4] = fmaf(v, w1.x, acc[ 4]); acc[ 5] = fmaf(v, w1.y, acc[ 5]);
            acc[ 6] = fmaf(v, w1.z, acc[ 6]); acc[ 7] = fmaf(v, w1.w, acc[ 7]);
            acc[ 8] = fmaf(v, w2.x, acc[ 8]); acc[ 9] = fmaf(v, w2.y, acc[ 9]);
            acc[10] = fmaf(v, w2.z, acc[10]); acc[11] = fmaf(v, w2.w, acc[11]);
            acc[12] = fmaf(v, w3.x, acc[12]); acc[13] = fmaf(v, w3.y, acc[13]);
            acc[14] = fmaf(v, w3.z, acc[14]); acc[15] = fmaf(v, w3.w, acc[15]);
        }
    }
    // kq=1 partials -> LDS (stride 17: odd stride, 2 lanes/bank = free)
    if (kq == 1) {
#pragma unroll
        for (int j = 0; j < 16; ++j) red[(t - 256) * 17 + j] = acc[j];
    }
    __syncthreads();   // also: all s_tile reads done; pool reusable

    if (kq == 0) {
        const float4* bt4 = (const float4*)b_tcn;   // wave-uniform scalar loads
        float4 b0 = bt4[cg * 4 + 0], b1 = bt4[cg * 4 + 1];
        float4 b2 = bt4[cg * 4 + 2], b3 = bt4[cg * 4 + 3];
        float bt[16] = {b0.x, b0.y, b0.z, b0.w, b1.x, b1.y, b1.z, b1.w,
                        b2.x, b2.y, b2.z, b2.w, b3.x, b3.y, b3.z, b3.w};
#pragma unroll
        for (int j = 0; j < 16; ++j) {
            float s2 = acc[j] + red[t * 17 + j];
            pool[(cg * 16 + j) * 65 + row] = fmaxf(s2 + bt[j], 0.f);  // hl[o][row]
        }
    }
    __syncthreads();

    // epilogue: 768 outputs = 64 rows (n,b encoded) x 12 p
    for (int out = t; out < 64 * PP; out += 512) {
        int r2 = out & 63, p = out >> 6;       // p in 0..11
        int n = n0 + (r2 >> 1), b = r2 & 1;
        float yy = b_out[p];
#pragma unroll 8
        for (int o = 0; o < HH; ++o)
            yy = fmaf(pool[o * 65 + r2], Wo[o * PP + p], yy);
        if (n < NN) y[((size_t)(b * PP + p)) * NN + n] = yy;
    }
}

// ---------------------------------------------------------------------------
extern "C" void kernel_launch(void* const* d_in, const int* in_sizes, int n_in,
                              void* d_out, int out_size, void* d_ws, size_t ws_size,
                              hipStream_t stream) {
    const float* x     = (const float*)d_in[0];
    const int*   row   = (const int*)d_in[1];
    const int*   col   = (const int*)d_in[2];
    const float* vals  = (const float*)d_in[3];
    const float* W_in  = (const float*)d_in[4];
    const float* b_in  = (const float*)d_in[5];
    const float* W_tcn = (const float*)d_in[6];
    const float* b_tcn = (const float*)d_in[7];
    const float* W_out = (const float*)d_in[8];
    const float* b_out = (const float*)d_in[9];
    float* y = (float*)d_out;

    char* ws = (char*)d_ws;
    float* hsmall = (float*)(ws);                    // 10,240,000 B
    int*   deg    = (int*)(ws + 10240000);           //     40,000 B
    int2*  bucket = (int2*)(ws + 10280000);          //  5,120,000 B
    float* h2     = (float*)(ws + 15400000);         // 10,240,000 B
    float* Wt     = (float*)(ws + 25640000);         //     32,768 B

    k1_input_proj<<<NN / 4, 256, 0, stream>>>(x, W_in, b_in, hsmall, deg);
    k2_build<<<(EE + 3 * HH * HH + 255) / 256, 256, 0, stream>>>(
        row, col, vals, deg, bucket, W_tcn, Wt);
    k3_gather<<<NN / 4, 256, 0, stream>>>(hsmall, deg, bucket, h2);
    // 32 nodes (64 rows) per block, 512 threads (split-K x2) -> 313 blocks
    k4_head<<<(NN + 31) / 32, 512, 0, stream>>>(h2, Wt, b_tcn, W_out, b_out, y);
}

// Round 11
// 110.576 us; speedup vs baseline: 1.1527x; 1.0096x over previous
//
#include <hip/hip_runtime.h>

// Problem constants: B=2, L=16, N=10000, FIN=8, H=64, P=12, E=80000, K=3
#define NN   10000
#define LL   16
#define FINC 8
#define HH   64
#define PP   12
#define EE   80000
#define BLH  256   // (b,lp,h) = 2*2*64 — only l=14,15 feed out[:,:,-1] (K=3, pad=1)
#define CAP  64    // per-row edge bucket capacity; E/N = 8, P(deg>64) ~ 0
#define RS   132   // k4 row stride (pad 128+4): 16B-aligned, odd bank phase per row

// ---------------------------------------------------------------------------
// k1 v3: 2500 blocks x 256 threads, 4 nodes per block (fully unrolled).
// W_in held in 8 registers; x read via wave-uniform scalar loads; no LDS,
// no sync. Blocks 0..39 zero deg.
// ---------------------------------------------------------------------------
__global__ __launch_bounds__(256) void k1_input_proj(
        const float* __restrict__ x, const float* __restrict__ W_in,
        const float* __restrict__ b_in, float* __restrict__ hsmall,
        int* __restrict__ deg) {
    const int t  = threadIdx.x;
    const int bl = __builtin_amdgcn_readfirstlane(t >> 6);  // wave-uniform (b*2+lp)
    const int h  = t & 63;
    const int b  = bl >> 1, lp = bl & 1;

    if (blockIdx.x < 40) {                 // zero deg (10000 ints over 40 blocks)
        int di = blockIdx.x * 256 + t;
        if (di < NN) deg[di] = 0;
    }

    float w[FINC];
#pragma unroll
    for (int f = 0; f < FINC; ++f) w[f] = W_in[f * HH + h];   // coalesced, L2-hot
    const float bias = b_in[h];
    const float* xb = x + (size_t)(b * LL + 14 + lp) * NN * FINC;
    const int g = blockIdx.x * 4;

#pragma unroll
    for (int nn = 0; nn < 4; ++nn) {
        const int n = g + nn;
        float4 xa = *(const float4*)&xb[(size_t)n * 8];       // uniform -> s_load
        float4 xc = *(const float4*)&xb[(size_t)n * 8 + 4];
        float acc = bias;
        acc = fmaf(xa.x, w[0], acc); acc = fmaf(xa.y, w[1], acc);
        acc = fmaf(xa.z, w[2], acc); acc = fmaf(xa.w, w[3], acc);
        acc = fmaf(xc.x, w[4], acc); acc = fmaf(xc.y, w[5], acc);
        acc = fmaf(xc.z, w[6], acc); acc = fmaf(xc.w, w[7], acc);
        hsmall[(size_t)n * BLH + t] = fmaxf(acc, 0.f);
    }
}

// ---------------------------------------------------------------------------
// k2: bucketed CSR build + pack W_tcn taps {0,1} into Wt[k][o] (k = lp*64+i).
// ---------------------------------------------------------------------------
__global__ __launch_bounds__(256) void k2_build(
        const int* __restrict__ row, const int* __restrict__ col,
        const float* __restrict__ vals, int* __restrict__ deg,
        int2* __restrict__ bucket, const float* __restrict__ W_tcn,
        float* __restrict__ Wt) {
    int e = blockIdx.x * 256 + threadIdx.x;
    if (e < EE) {
        int r = row[e];
        int pos = atomicAdd(&deg[r], 1);
        if (pos < CAP)
            bucket[(size_t)r * CAP + pos] = make_int2(col[e], __float_as_int(vals[e]));
    } else if (e < EE + 3 * HH * HH) {
        int f = e - EE;                 // linear index into W_tcn [o][i][k3]
        int kk = f % 3;
        if (kk < 2) {
            int o = f / (HH * 3);
            int i = (f / 3) % HH;
            Wt[(kk * HH + i) * HH + o] = W_tcn[f];
        }
    }
}

// ---------------------------------------------------------------------------
// k3: gather-aggregate, zero LDS. One wave per node; metadata via one
// coalesced 512B load + shfl broadcast (entries >= deg masked to {0, 0.0});
// 8 independent row loads in flight.
// ---------------------------------------------------------------------------
__global__ __launch_bounds__(256) void k3_gather(
        const float* __restrict__ hsmall, const int* __restrict__ deg,
        const int2* __restrict__ bucket, float* __restrict__ h2) {
    const int wave = threadIdx.x >> 6;
    const int lane = threadIdx.x & 63;
    const int n = blockIdx.x * 4 + wave;
    const int dn  = min(deg[n], CAP);
    const int dnp = (dn + 7) & ~7;
    const int2 meta = bucket[(size_t)n * CAP + lane];   // poison beyond dn — masked

    float4 acc = make_float4(0.f, 0.f, 0.f, 0.f);
    for (int i = 0; i < dnp; i += 8) {
        int   c[8];
        float v[8];
#pragma unroll
        for (int j = 0; j < 8; ++j) {
            int idx = i + j;
            int   cc = __shfl(meta.x, idx);
            float vv = __int_as_float(__shfl(meta.y, idx));
            bool ok = idx < dn;
            c[j] = ok ? cc : 0;
            v[j] = ok ? vv : 0.f;
        }
        float4 hv[8];
#pragma unroll
        for (int j = 0; j < 8; ++j)
            hv[j] = *(const float4*)&hsmall[(size_t)c[j] * BLH + lane * 4];
#pragma unroll
        for (int j = 0; j < 8; ++j) {
            acc.x = fmaf(v[j], hv[j].x, acc.x);
            acc.y = fmaf(v[j], hv[j].y, acc.y);
            acc.z = fmaf(v[j], hv[j].z, acc.z);
            acc.w = fmaf(v[j], hv[j].w, acc.w);
        }
    }
    float4 r = make_float4(fmaxf(acc.x, 0.f), fmaxf(acc.y, 0.f),
                           fmaxf(acc.z, 0.f), fmaxf(acc.w, 0.f));
    *(float4*)&h2[(size_t)n * BLH + lane * 4] = r;
}

// ---------------------------------------------------------------------------
// k4 v5: head GEMM, split-K x2, acc[8], 1024 threads — occupancy x2 over r10
// while keeping ds_read_b128 + wave-uniform s_load structure intact.
// M=20000 rows (n,b), K=128, N=64 (o).  1024 threads = 64 rows x 8 o-groups
// x 2 K-halves; thread = 1 row x 8 o over 64 k, 4 k per ds_read_b128
// (32 FMA per LDS read).  Wt via wave-uniform s_loads (2x16B per k);
// cross-half reduction through stride-9 LDS (9 coprime 32, conflict-free);
// pool reused as hl[o][row].
// ---------------------------------------------------------------------------
__global__ __launch_bounds__(1024, 8) void k4_head(
        const float* __restrict__ h2, const float* __restrict__ Wt,
        const float* __restrict__ b_tcn, const float* __restrict__ W_out,
        const float* __restrict__ b_out, float* __restrict__ y) {
    __shared__ float pool[64 * RS];    // 33.8 KB: s_tile[row][k], then hl[o*65+row]
    __shared__ float red[512 * 9];     // 18.4 KB: kq=1 partials, stride-9
    __shared__ float Wo[HH * PP];      // 3 KB
    const int t   = threadIdx.x;       // 0..1023
    const int row = t & 63;
    const int og  = __builtin_amdgcn_readfirstlane((t >> 6) & 7);  // wave-uniform
    const int kq  = __builtin_amdgcn_readfirstlane(t >> 9);        // wave-uniform
    const int n0  = blockIdx.x * 32;

    for (int idx = t; idx < HH * PP; idx += 1024) Wo[idx] = W_out[idx];
    // stage s_tile[row][k]: coalesced float4 loads, aligned b128 LDS writes
    const float4* h2v = (const float4*)h2;
    for (int idx4 = t; idx4 < 32 * (BLH / 4); idx4 += 1024) {
        int nn = idx4 >> 6, q = idx4 & 63;       // b=q>>5, k0=(q&31)*4
        int r  = nn * 2 + (q >> 5);
        int k0 = (q & 31) * 4;
        float4 v = make_float4(0.f, 0.f, 0.f, 0.f);
        if (n0 + nn < NN) v = h2v[(size_t)(n0 + nn) * (BLH / 4) + q];
        *(float4*)&pool[r * RS + k0] = v;        // RS*4 % 16 == 0 -> aligned
    }
    __syncthreads();

    const float4* Wt4 = (const float4*)Wt;    // Wt[k*64+o] -> float4 idx k*16+o/4
    float acc[8];
#pragma unroll
    for (int j = 0; j < 8; ++j) acc[j] = 0.f;

    const int kbase = kq * 64;
#pragma unroll 4
    for (int kk = 0; kk < 16; ++kk) {
        const int k0 = kbase + kk * 4;
        float4 s4 = *(const float4*)&pool[row * RS + k0];   // 1 ds_read_b128 = 4 k
        float sv[4] = {s4.x, s4.y, s4.z, s4.w};
#pragma unroll
        for (int j = 0; j < 4; ++j) {
            const int k = k0 + j;
            float4 w0 = Wt4[k * 16 + og * 2 + 0];   // wave-uniform -> s_load
            float4 w1 = Wt4[k * 16 + og * 2 + 1];
            float v = sv[j];
            acc[0] = fmaf(v, w0.x, acc[0]); acc[1] = fmaf(v, w0.y, acc[1]);
            acc[2] = fmaf(v, w0.z, acc[2]); acc[3] = fmaf(v, w0.w, acc[3]);
            acc[4] = fmaf(v, w1.x, acc[4]); acc[5] = fmaf(v, w1.y, acc[5]);
            acc[6] = fmaf(v, w1.z, acc[6]); acc[7] = fmaf(v, w1.w, acc[7]);
        }
    }
    // kq=1 partials -> LDS (stride 9, coprime 32 -> conflict-free)
    if (kq == 1) {
#pragma unroll
        for (int j = 0; j < 8; ++j) red[(t - 512) * 9 + j] = acc[j];
    }
    __syncthreads();   // also: all s_tile reads done; pool reusable

    if (kq == 0) {
        const float4* bt4 = (const float4*)b_tcn;   // wave-uniform scalar loads
        float4 b0 = bt4[og * 2 + 0], b1 = bt4[og * 2 + 1];
        float bt[8] = {b0.x, b0.y, b0.z, b0.w, b1.x, b1.y, b1.z, b1.w};
#pragma unroll
        for (int j = 0; j < 8; ++j) {
            float s2 = acc[j] + red[t * 9 + j];
            pool[(og * 8 + j) * 65 + row] = fmaxf(s2 + bt[j], 0.f);  // hl[o][row]
        }
    }
    __syncthreads();

    // epilogue: 768 outputs = 64 rows (n,b encoded) x 12 p
    if (t < 64 * PP) {
        int r2 = t & 63, p = t >> 6;           // p in 0..11
        int n = n0 + (r2 >> 1), b = r2 & 1;
        float yy = b_out[p];
#pragma unroll 8
        for (int o = 0; o < HH; ++o)
            yy = fmaf(pool[o * 65 + r2], Wo[o * PP + p], yy);
        if (n < NN) y[((size_t)(b * PP + p)) * NN + n] = yy;
    }
}

// ---------------------------------------------------------------------------
extern "C" void kernel_launch(void* const* d_in, const int* in_sizes, int n_in,
                              void* d_out, int out_size, void* d_ws, size_t ws_size,
                              hipStream_t stream) {
    const float* x     = (const float*)d_in[0];
    const int*   row   = (const int*)d_in[1];
    const int*   col   = (const int*)d_in[2];
    const float* vals  = (const float*)d_in[3];
    const float* W_in  = (const float*)d_in[4];
    const float* b_in  = (const float*)d_in[5];
    const float* W_tcn = (const float*)d_in[6];
    const float* b_tcn = (const float*)d_in[7];
    const float* W_out = (const float*)d_in[8];
    const float* b_out = (const float*)d_in[9];
    float* y = (float*)d_out;

    char* ws = (char*)d_ws;
    float* hsmall = (float*)(ws);                    // 10,240,000 B
    int*   deg    = (int*)(ws + 10240000);           //     40,000 B
    int2*  bucket = (int2*)(ws + 10280000);          //  5,120,000 B
    float* h2     = (float*)(ws + 15400000);         // 10,240,000 B
    float* Wt     = (float*)(ws + 25640000);         //     32,768 B

    k1_input_proj<<<NN / 4, 256, 0, stream>>>(x, W_in, b_in, hsmall, deg);
    k2_build<<<(EE + 3 * HH * HH + 255) / 256, 256, 0, stream>>>(
        row, col, vals, deg, bucket, W_tcn, Wt);
    k3_gather<<<NN / 4, 256, 0, stream>>>(hsmall, deg, bucket, h2);
    // 32 nodes (64 rows) per block, 1024 threads (8 og x 2 kq) -> 313 blocks
    k4_head<<<(NN + 31) / 32, 1024, 0, stream>>>(h2, Wt, b_tcn, W_out, b_out, y);
}